// Round 5
// baseline (199.251 us; speedup 1.0000x reference)
//
#include <hip/hip_runtime.h>
#include <math.h>

using u16 = unsigned short;
using u32 = unsigned int;

typedef __attribute__((ext_vector_type(8))) short bf16x8;
typedef __attribute__((ext_vector_type(16))) float f32x16;

// Problem constants
constexpr int Bn  = 8;                  // batch
constexpr int Cin = 16;                 // input channels
constexpr int Tn  = 160;
constexpr int HWn = 2304;               // 48*48
constexpr int Dn  = 160;                // rows of x3: d = ca*20 + t/8
constexpr int Nn  = 8 * HWn;            // 18432 cols: n = (t%8)*2304 + hw
constexpr int PB  = Dn * Nn;            // per-batch x3 elems
constexpr int PLANE4 = Tn * HWn / 4;    // 92160
constexpr float EPSF = 1e-6f;
constexpr float B0F  = 0.07905694150420949f;  // 1/sqrt(160)
constexpr float BTB0 = 160.0f * B0F * B0F;    // ||b0||^2

constexpr int NSPLIT = 72;              // k-splits (256 cols each)
constexpr int NTRI   = 15;              // upper-triangle 32x32 tiles of 160x160
constexpr int GD     = Dn * Dn;         // 25600

// d_out layout (floats): h (bf16, first 11.8M floats) | G
constexpr size_t G_OFF  = (size_t)Bn * PB / 2;        // 11796480

// ws layout (floats): coef [8*18432] | bases4 [8*160] | btb4 [8]
constexpr int OFF_COEF = 0;
constexpr int OFF_B4   = Bn * Nn;        // 147456
constexpr int OFF_BTB  = OFF_B4 + Bn * Dn;

// bf16 helpers (h is finite: no NaN handling needed)
__device__ inline float bf2f(u16 u) { return __uint_as_float(((u32)u) << 16); }
__device__ inline u16 f2bf(float f) {
    u32 x = __float_as_uint(f);
    return (u16)((x + 0x7fffu + ((x >> 16) & 1u)) >> 16);   // RNE
}

// upper-tri tile index t (0..14) -> strip pair (a, bb), a <= bb.
// list order: (0,0)(0,1)(0,2)(0,3)(0,4)(1,1)(1,2)(1,3)(1,4)(2,2)(2,3)(2,4)(3,3)(3,4)(4,4)
__device__ inline void tri_pair(int t, int& a, int& bb) {
    a = (t >= 14) ? 4 : (t >= 12) ? 3 : (t >= 9) ? 2 : (t >= 5) ? 1 : 0;
    int base = (a == 0) ? 0 : (a == 1) ? 5 : (a == 2) ? 9 : (a == 3) ? 12 : 14;
    bb = a + (t - base);
}

// ---------------------------------------------------------------------------
// h = relu(W_pre @ x), stored bf16 in [b][ca][t][hw] == x3 [b][d][n] layout
// (r6-proven). One thread = one float4 position, all 8 out channels.
// Additionally: first 200 blocks zero G (consumed by k_gram's atomicAdd).
__global__ __launch_bounds__(256) void k_pre(const float* __restrict__ x,
                                             const float* __restrict__ Wpre,
                                             u16* __restrict__ h,
                                             float* __restrict__ G) {
    __shared__ float Ws[8 * Cin];
    if (threadIdx.x < 8 * Cin) Ws[threadIdx.x] = Wpre[threadIdx.x];
    __syncthreads();
    int gid = blockIdx.x * 256 + threadIdx.x;
    // zero G: 8*25600 floats = 51200 float4
    if (gid < Bn * GD / 4) {
        reinterpret_cast<float4*>(G)[gid] = make_float4(0.f, 0.f, 0.f, 0.f);
    }
    int b   = gid / PLANE4;
    int pos = gid - b * PLANE4;
    const float4* xb = reinterpret_cast<const float4*>(x) + (size_t)(b * Cin) * PLANE4 + pos;
    float4 acc[8];
#pragma unroll
    for (int o = 0; o < 8; ++o) acc[o] = make_float4(0.f, 0.f, 0.f, 0.f);
#pragma unroll
    for (int c = 0; c < Cin; ++c) {
        float4 xv = xb[(size_t)c * PLANE4];
#pragma unroll
        for (int o = 0; o < 8; ++o) {
            float w = Ws[o * Cin + c];
            acc[o].x = fmaf(w, xv.x, acc[o].x);
            acc[o].y = fmaf(w, xv.y, acc[o].y);
            acc[o].z = fmaf(w, xv.z, acc[o].z);
            acc[o].w = fmaf(w, xv.w, acc[o].w);
        }
    }
#pragma unroll
    for (int o = 0; o < 8; ++o) {
        float4 v = acc[o];
        u32 w0 = (u32)f2bf(fmaxf(v.x, 0.f)) | ((u32)f2bf(fmaxf(v.y, 0.f)) << 16);
        u32 w1 = (u32)f2bf(fmaxf(v.z, 0.f)) | ((u32)f2bf(fmaxf(v.w, 0.f)) << 16);
        uint2* dst = reinterpret_cast<uint2*>(h + (size_t)(b * 8 + o) * (Tn * HWn)) + pos;
        *dst = make_uint2(w0, w1);
    }
}

// ---------------------------------------------------------------------------
// Gram partials, upper-triangle only (G symmetric): 15 tiles, 4 waves own
// {w, w+4, w+8, w+12}; diag tiles reuse one fragment. Grid 576 blocks
// (8 b x 72 splits of 256 cols = 2 chunks x 128), 256 thr. r0-proven compute;
// epilogue changed: atomicAdd into L2-resident G (800 KB) instead of a
// 35 MB Gpart HBM round-trip. atomicAdd is device-scope (cross-XCD safe).
__global__ __launch_bounds__(256, 3) void k_gram(const u16* __restrict__ h,
                                                 float* __restrict__ G) {
    __shared__ uint4 tile[Dn * 16];      // 40 KB: [row][slot], slot = 16B (8 bf16)
    const int blk = blockIdx.x;
    const int b = blk / NSPLIT, s = blk - b * NSPLIT;
    const int tid = threadIdx.x;
    const int w = tid >> 6, l = tid & 63, lo = l & 31, hi = l >> 5;
    const int c8 = tid & 15, rg = tid >> 4;     // staging coords
    const int swl = lo & 7;

    // wave's tiles (setup once; wave-uniform scalars)
    int a0, b0_, a1, b1_, a2, b2_, a3, b3_;
    tri_pair(w,      a0, b0_);
    tri_pair(w + 4,  a1, b1_);
    tri_pair(w + 8,  a2, b2_);
    const bool has3 = (w < 3);
    tri_pair(has3 ? (w + 12) : 0, a3, b3_);
    const int rA0 = a0 * 32, rB0 = b0_ * 32, dg0 = (a0 == b0_);
    const int rA1 = a1 * 32, rB1 = b1_ * 32, dg1 = (a1 == b1_);
    const int rA2 = a2 * 32, rB2 = b2_ * 32, dg2 = (a2 == b2_);
    const int rA3 = a3 * 32, rB3 = b3_ * 32, dg3 = (a3 == b3_);

    f32x16 acc0, acc1, acc2, acc3;
#pragma unroll
    for (int q = 0; q < 16; ++q) { acc0[q] = 0.f; acc1[q] = 0.f; acc2[q] = 0.f; acc3[q] = 0.f; }

    const u16* hb = h + (size_t)b * PB;
#pragma unroll 1
    for (int cc = 0; cc < 2; ++cc) {
        const int kbase = (s * 2 + cc) * 128;
        __syncthreads();                 // prior MFMA phase done before restage
#pragma unroll
        for (int k = 0; k < 10; ++k) {
            int row = rg + 16 * k;
            uint4 v = *reinterpret_cast<const uint4*>(
                hb + (size_t)row * Nn + kbase + c8 * 8);
            tile[row * 16 + (c8 ^ (row & 7))] = v;
        }
        __syncthreads();
#pragma unroll
        for (int kk = 0; kk < 8; ++kk) {
            const int sw = (kk * 2 + hi) ^ swl;
            bf16x8 fa0 = __builtin_bit_cast(bf16x8, tile[(rA0 + lo) * 16 + sw]);
            bf16x8 fb0 = dg0 ? fa0 : __builtin_bit_cast(bf16x8, tile[(rB0 + lo) * 16 + sw]);
            acc0 = __builtin_amdgcn_mfma_f32_32x32x16_bf16(fa0, fb0, acc0, 0, 0, 0);
            bf16x8 fa1 = __builtin_bit_cast(bf16x8, tile[(rA1 + lo) * 16 + sw]);
            bf16x8 fb1 = dg1 ? fa1 : __builtin_bit_cast(bf16x8, tile[(rB1 + lo) * 16 + sw]);
            acc1 = __builtin_amdgcn_mfma_f32_32x32x16_bf16(fa1, fb1, acc1, 0, 0, 0);
            bf16x8 fa2 = __builtin_bit_cast(bf16x8, tile[(rA2 + lo) * 16 + sw]);
            bf16x8 fb2 = dg2 ? fa2 : __builtin_bit_cast(bf16x8, tile[(rB2 + lo) * 16 + sw]);
            acc2 = __builtin_amdgcn_mfma_f32_32x32x16_bf16(fa2, fb2, acc2, 0, 0, 0);
            if (has3) {
                bf16x8 fa3 = __builtin_bit_cast(bf16x8, tile[(rA3 + lo) * 16 + sw]);
                bf16x8 fb3 = dg3 ? fa3 : __builtin_bit_cast(bf16x8, tile[(rB3 + lo) * 16 + sw]);
                acc3 = __builtin_amdgcn_mfma_f32_32x32x16_bf16(fa3, fb3, acc3, 0, 0, 0);
            }
        }
    }

    // C/D layout (r10 end-to-end validated): col=lo, row=(q&3)+8*(q>>2)+4*hi
    // (i, j) = (a*32 + row, bb*32 + lo); accumulate into upper-tri of G.
    float* Gb = G + (size_t)b * GD;
#pragma unroll
    for (int q = 0; q < 16; ++q) {
        int R = (q & 3) + 8 * (q >> 2) + 4 * hi;
        atomicAdd(&Gb[(a0 * 32 + R) * Dn + b0_ * 32 + lo], acc0[q]);
        atomicAdd(&Gb[(a1 * 32 + R) * Dn + b1_ * 32 + lo], acc1[q]);
        atomicAdd(&Gb[(a2 * 32 + R) * Dn + b2_ * 32 + lo], acc2[q]);
        if (has3) atomicAdd(&Gb[(a3 * 32 + R) * Dn + b3_ * 32 + lo], acc3[q]);
    }
}

// ---------------------------------------------------------------------------
// 4-step power-iteration chain on G (r0-proven serial version), reading the
// upper triangle only: element (i,d) lives at [min*Dn + max]. G is L2-hot.
__global__ __launch_bounds__(192) void k_chainB(const float* __restrict__ G,
                                                float* __restrict__ bases4,
                                                float* __restrict__ btb4) {
    __shared__ float bS[Dn];
    __shared__ float uS[Dn];
    __shared__ float sc[2];
    const int b = blockIdx.x;
    const int tid = threadIdx.x;
    const float* Gb = G + (size_t)b * GD;

    if (tid < Dn) bS[tid] = B0F;
    __syncthreads();

    float btb = BTB0;
#pragma unroll 1
    for (int j = 1; j <= 4; ++j) {
        if (tid < Dn) {
            float s = 0.f;
#pragma unroll 8
            for (int d = 0; d < Dn; ++d) {
                float g = (tid <= d) ? Gb[tid * Dn + d] : Gb[d * Dn + tid];
                s = fmaf(g, bS[d], s);
            }
            uS[tid] = s;
        }
        __syncthreads();
        if (tid == 0) {
            float bgb = 0.f;
            for (int d = 0; d < Dn; ++d) bgb = fmaf(bS[d], uS[d], bgb);
            sc[0] = bgb;
        }
        __syncthreads();
        float denom = (j == 1) ? (btb + EPSF) : btb;
        float ctc = sc[0] / (denom * denom);
        float inv = 1.f / (denom * ctc);
        if (tid < Dn) bS[tid] = uS[tid] * inv;
        __syncthreads();
        if (tid == 0) {
            float ss = 0.f;
            for (int d = 0; d < Dn; ++d) ss = fmaf(bS[d], bS[d], ss);
            sc[1] = ss;
        }
        __syncthreads();
        btb = sc[1];
    }
    if (tid < Dn) bases4[b * Dn + tid] = bS[tid];
    if (tid == 0) btb4[b] = btb;
}

// ---------------------------------------------------------------------------
// Final coef: coef5[n] = (X^T b4)[n] / btb4 (r10-proven).
__global__ __launch_bounds__(256, 3) void k_coef5(
        const u16* __restrict__ h, float* __restrict__ coef,
        const float* __restrict__ bases4, const float* __restrict__ btb4)
{
    __shared__ float bsS[Dn];
    __shared__ float partA[4][128];
    const int blk = blockIdx.x;
    const int b   = blk / 144;
    const int cb  = blk - b * 144;
    const int colbase = cb * 128;
    const int tid = threadIdx.x, c8 = tid & 15, rg = tid >> 4;

    if (tid < Dn) bsS[tid] = bases4[b * Dn + tid] / btb4[b];
    __syncthreads();

    const u16* hp = h + (size_t)b * PB + colbase + c8 * 8;
    float acc[8];
#pragma unroll
    for (int j = 0; j < 8; ++j) acc[j] = 0.f;
#pragma unroll
    for (int k = 0; k < 10; ++k) {
        uint4 v = *reinterpret_cast<const uint4*>(hp + (size_t)(rg + 16 * k) * Nn);
        float w = bsS[rg + 16 * k];
        u32 vv[4] = { v.x, v.y, v.z, v.w };
#pragma unroll
        for (int q = 0; q < 4; ++q) {
            acc[2*q]   = fmaf(w, bf2f((u16)(vv[q] & 0xffffu)), acc[2*q]);
            acc[2*q+1] = fmaf(w, bf2f((u16)(vv[q] >> 16)),     acc[2*q+1]);
        }
    }
#pragma unroll
    for (int j = 0; j < 8; ++j) {
        acc[j] += __shfl_xor(acc[j], 16, 64);
        acc[j] += __shfl_xor(acc[j], 32, 64);
    }
    if ((tid & 48) == 0) {
        int w = tid >> 6;
#pragma unroll
        for (int j = 0; j < 8; ++j) partA[w][c8 * 8 + j] = acc[j];
    }
    __syncthreads();

    if (tid < 128)
        coef[(size_t)b * Nn + colbase + tid] =
            partA[0][tid] + partA[1][tid] + partA[2][tid] + partA[3][tid];
}

// ---------------------------------------------------------------------------
// Final output (r1-proven): out[b,o,t,hw] = coef5[n] * v[o,tau];
// relu(coef*u) == coef*relu(u) since coef5 >= 0. Grid 8*160, 192 thr.
__global__ __launch_bounds__(192) void k_post(const float* __restrict__ coef,
                                              const float* __restrict__ bases,
                                              const float* __restrict__ Wp1,
                                              const float* __restrict__ Wp2,
                                              float* __restrict__ out) {
    int b = blockIdx.x / Tn;
    int t = blockIdx.x - b * Tn;
    int tau = t >> 3;
    float u[8];
#pragma unroll
    for (int p = 0; p < 8; ++p) {
        float s = 0.f;
#pragma unroll
        for (int ca = 0; ca < 8; ++ca)
            s = fmaf(Wp1[p * 8 + ca], bases[b * Dn + ca * 20 + tau], s);
        u[p] = fmaxf(s, 0.f);
    }
    float v[16];
#pragma unroll
    for (int o = 0; o < 16; ++o) {
        float s = 0.f;
#pragma unroll
        for (int p = 0; p < 8; ++p) s = fmaf(Wp2[o * 8 + p], u[p], s);
        v[o] = s;
    }
    const float4* c4 = reinterpret_cast<const float4*>(coef + (size_t)b * Nn + (t & 7) * HWn);
    float4* o4 = reinterpret_cast<float4*>(out) + (size_t)(b * 16 * Tn + t) * (HWn / 4);
#pragma unroll
    for (int it = 0; it < 3; ++it) {
        int p4 = threadIdx.x + it * 192;
        float4 cv = c4[p4];
#pragma unroll
        for (int o = 0; o < 16; ++o) {
            float4 ov = make_float4(cv.x * v[o], cv.y * v[o], cv.z * v[o], cv.w * v[o]);
            o4[(size_t)o * (Tn * (HWn / 4)) + p4] = ov;
        }
    }
}

// ---------------------------------------------------------------------------
extern "C" void kernel_launch(void* const* d_in, const int* in_sizes, int n_in,
                              void* d_out, int out_size, void* d_ws, size_t ws_size,
                              hipStream_t stream) {
    const float* x    = (const float*)d_in[0];
    const float* Wpre = (const float*)d_in[1];
    const float* Wp1  = (const float*)d_in[2];
    const float* Wp2  = (const float*)d_in[3];
    float* out = (float*)d_out;

    // d_out: h (47 MB bf16) | G (820 KB) — all consumed before k_post
    // rewrites d_out (k_post reads only ws). G is zeroed by k_pre, then
    // accumulated by k_gram's atomicAdd (L2-resident; no HBM round-trip).
    u16*   h     = (u16*)d_out;
    float* G     = out + G_OFF;
    float* ws = (float*)d_ws;
    float* coef   = ws + OFF_COEF;
    float* bases4 = ws + OFF_B4;
    float* btb4   = ws + OFF_BTB;

    k_pre<<<Bn * PLANE4 / 256, 256, 0, stream>>>(x, Wpre, h, G);
    k_gram<<<Bn * NSPLIT, 256, 0, stream>>>(h, G);
    k_chainB<<<Bn, 192, 0, stream>>>(G, bases4, btb4);
    k_coef5<<<Bn * 144, 256, 0, stream>>>(h, coef, bases4, btb4);
    k_post<<<Bn * Tn, 192, 0, stream>>>(coef, bases4, Wp1, Wp2, out);
}

// Round 6
// 147.953 us; speedup vs baseline: 1.3467x; 1.3467x over previous
//
#include <hip/hip_runtime.h>
#include <math.h>

using u16 = unsigned short;
using u32 = unsigned int;

typedef __attribute__((ext_vector_type(8))) short bf16x8;
typedef __attribute__((ext_vector_type(16))) float f32x16;

// Problem constants
constexpr int Bn  = 8;                  // batch
constexpr int Cin = 16;                 // input channels
constexpr int Tn  = 160;
constexpr int HWn = 2304;               // 48*48
constexpr int Dn  = 160;                // rows of x3: d = ca*20 + t/8
constexpr int Nn  = 8 * HWn;            // 18432 cols: n = (t%8)*2304 + hw
constexpr int PB  = Dn * Nn;            // per-batch x3 elems
constexpr int PLANE4 = Tn * HWn / 4;    // 92160
constexpr float EPSF = 1e-6f;
constexpr float B0F  = 0.07905694150420949f;  // 1/sqrt(160)
constexpr float BTB0 = 160.0f * B0F * B0F;    // ||b0||^2

constexpr int NSPLIT = 48;              // k-splits (384 cols each = 3 chunks x 128)
constexpr int NTRI   = 15;              // upper-triangle 32x32 tiles of 160x160
constexpr int TSZ    = NTRI * 1024;     // compact floats per partial = 15360
constexpr int GD     = Dn * Dn;         // 25600

// d_out layout (floats): h (bf16, first 11.8M floats) | G | Gpart(compact)
constexpr size_t G_OFF  = (size_t)Bn * PB / 2;        // 11796480
constexpr size_t GP_OFF = G_OFF + (size_t)Bn * GD;    // + 204800

// ws layout (floats): coef [8*18432] | bases4 [8*160] | btb4 [8]
constexpr int OFF_COEF = 0;
constexpr int OFF_B4   = Bn * Nn;        // 147456
constexpr int OFF_BTB  = OFF_B4 + Bn * Dn;

// bf16 helpers (h is finite: no NaN handling needed)
__device__ inline float bf2f(u16 u) { return __uint_as_float(((u32)u) << 16); }
__device__ inline u16 f2bf(float f) {
    u32 x = __float_as_uint(f);
    return (u16)((x + 0x7fffu + ((x >> 16) & 1u)) >> 16);   // RNE
}

// upper-tri tile index t (0..14) -> strip pair (a, bb), a <= bb.
// list order: (0,0)(0,1)(0,2)(0,3)(0,4)(1,1)(1,2)(1,3)(1,4)(2,2)(2,3)(2,4)(3,3)(3,4)(4,4)
__device__ inline void tri_pair(int t, int& a, int& bb) {
    a = (t >= 14) ? 4 : (t >= 12) ? 3 : (t >= 9) ? 2 : (t >= 5) ? 1 : 0;
    int base = (a == 0) ? 0 : (a == 1) ? 5 : (a == 2) ? 9 : (a == 3) ? 12 : 14;
    bb = a + (t - base);
}

// ---------------------------------------------------------------------------
// h = relu(W_pre @ x), stored bf16 in [b][ca][t][hw] == x3 [b][d][n] layout
// (r6-proven). One thread = one float4 position, all 8 out channels.
__global__ __launch_bounds__(256) void k_pre(const float* __restrict__ x,
                                             const float* __restrict__ Wpre,
                                             u16* __restrict__ h) {
    __shared__ float Ws[8 * Cin];
    if (threadIdx.x < 8 * Cin) Ws[threadIdx.x] = Wpre[threadIdx.x];
    __syncthreads();
    int gid = blockIdx.x * 256 + threadIdx.x;
    int b   = gid / PLANE4;
    int pos = gid - b * PLANE4;
    const float4* xb = reinterpret_cast<const float4*>(x) + (size_t)(b * Cin) * PLANE4 + pos;
    float4 acc[8];
#pragma unroll
    for (int o = 0; o < 8; ++o) acc[o] = make_float4(0.f, 0.f, 0.f, 0.f);
#pragma unroll
    for (int c = 0; c < Cin; ++c) {
        float4 xv = xb[(size_t)c * PLANE4];
#pragma unroll
        for (int o = 0; o < 8; ++o) {
            float w = Ws[o * Cin + c];
            acc[o].x = fmaf(w, xv.x, acc[o].x);
            acc[o].y = fmaf(w, xv.y, acc[o].y);
            acc[o].z = fmaf(w, xv.z, acc[o].z);
            acc[o].w = fmaf(w, xv.w, acc[o].w);
        }
    }
#pragma unroll
    for (int o = 0; o < 8; ++o) {
        float4 v = acc[o];
        u32 w0 = (u32)f2bf(fmaxf(v.x, 0.f)) | ((u32)f2bf(fmaxf(v.y, 0.f)) << 16);
        u32 w1 = (u32)f2bf(fmaxf(v.z, 0.f)) | ((u32)f2bf(fmaxf(v.w, 0.f)) << 16);
        uint2* dst = reinterpret_cast<uint2*>(h + (size_t)(b * 8 + o) * (Tn * HWn)) + pos;
        *dst = make_uint2(w0, w1);
    }
}

// ---------------------------------------------------------------------------
// Gram partials, upper-triangle only (G symmetric): 15 tiles, 4 waves own
// {w, w+4, w+8, w+12}; diag tiles reuse one fragment. Grid 384 blocks
// (8 b x 48 splits of 384 cols = 3 chunks x 128), 256 thr. Named accs
// (rule #20), compact Gpart [blk][15][1024]. r0-proven structure; only the
// chunk count per block changed (2 -> 3, NSPLIT 72 -> 48) to halve-ish the
// Gpart HBM round-trip.
__global__ __launch_bounds__(256, 3) void k_gram(const u16* __restrict__ h,
                                                 float* __restrict__ Gpart) {
    __shared__ uint4 tile[Dn * 16];      // 40 KB: [row][slot], slot = 16B (8 bf16)
    const int blk = blockIdx.x;
    const int b = blk / NSPLIT, s = blk - b * NSPLIT;
    const int tid = threadIdx.x;
    const int w = tid >> 6, l = tid & 63, lo = l & 31, hi = l >> 5;
    const int c8 = tid & 15, rg = tid >> 4;     // staging coords
    const int swl = lo & 7;

    // wave's tiles (setup once; wave-uniform scalars)
    int a0, b0_, a1, b1_, a2, b2_, a3, b3_;
    tri_pair(w,      a0, b0_);
    tri_pair(w + 4,  a1, b1_);
    tri_pair(w + 8,  a2, b2_);
    const bool has3 = (w < 3);
    tri_pair(has3 ? (w + 12) : 0, a3, b3_);
    const int rA0 = a0 * 32, rB0 = b0_ * 32, dg0 = (a0 == b0_);
    const int rA1 = a1 * 32, rB1 = b1_ * 32, dg1 = (a1 == b1_);
    const int rA2 = a2 * 32, rB2 = b2_ * 32, dg2 = (a2 == b2_);
    const int rA3 = a3 * 32, rB3 = b3_ * 32, dg3 = (a3 == b3_);

    f32x16 acc0, acc1, acc2, acc3;
#pragma unroll
    for (int q = 0; q < 16; ++q) { acc0[q] = 0.f; acc1[q] = 0.f; acc2[q] = 0.f; acc3[q] = 0.f; }

    const u16* hb = h + (size_t)b * PB;
#pragma unroll 1
    for (int cc = 0; cc < 3; ++cc) {
        const int kbase = (s * 3 + cc) * 128;
        __syncthreads();                 // prior MFMA phase done before restage
#pragma unroll
        for (int k = 0; k < 10; ++k) {
            int row = rg + 16 * k;
            uint4 v = *reinterpret_cast<const uint4*>(
                hb + (size_t)row * Nn + kbase + c8 * 8);
            tile[row * 16 + (c8 ^ (row & 7))] = v;
        }
        __syncthreads();
#pragma unroll
        for (int kk = 0; kk < 8; ++kk) {
            const int sw = (kk * 2 + hi) ^ swl;
            bf16x8 fa0 = __builtin_bit_cast(bf16x8, tile[(rA0 + lo) * 16 + sw]);
            bf16x8 fb0 = dg0 ? fa0 : __builtin_bit_cast(bf16x8, tile[(rB0 + lo) * 16 + sw]);
            acc0 = __builtin_amdgcn_mfma_f32_32x32x16_bf16(fa0, fb0, acc0, 0, 0, 0);
            bf16x8 fa1 = __builtin_bit_cast(bf16x8, tile[(rA1 + lo) * 16 + sw]);
            bf16x8 fb1 = dg1 ? fa1 : __builtin_bit_cast(bf16x8, tile[(rB1 + lo) * 16 + sw]);
            acc1 = __builtin_amdgcn_mfma_f32_32x32x16_bf16(fa1, fb1, acc1, 0, 0, 0);
            bf16x8 fa2 = __builtin_bit_cast(bf16x8, tile[(rA2 + lo) * 16 + sw]);
            bf16x8 fb2 = dg2 ? fa2 : __builtin_bit_cast(bf16x8, tile[(rB2 + lo) * 16 + sw]);
            acc2 = __builtin_amdgcn_mfma_f32_32x32x16_bf16(fa2, fb2, acc2, 0, 0, 0);
            if (has3) {
                bf16x8 fa3 = __builtin_bit_cast(bf16x8, tile[(rA3 + lo) * 16 + sw]);
                bf16x8 fb3 = dg3 ? fa3 : __builtin_bit_cast(bf16x8, tile[(rB3 + lo) * 16 + sw]);
                acc3 = __builtin_amdgcn_mfma_f32_32x32x16_bf16(fa3, fb3, acc3, 0, 0, 0);
            }
        }
    }

    // C/D layout (r10 end-to-end validated): col=lo, row=(q&3)+8*(q>>2)+4*hi
    float* Gp = Gpart + (size_t)blk * TSZ;
#pragma unroll
    for (int q = 0; q < 16; ++q) {
        int row = ((q & 3) + 8 * (q >> 2) + 4 * hi) * 32 + lo;
        Gp[(w)      * 1024 + row] = acc0[q];
        Gp[(w + 4)  * 1024 + row] = acc1[q];
        Gp[(w + 8)  * 1024 + row] = acc2[q];
        if (has3) Gp[(w + 12) * 1024 + row] = acc3[q];
    }
}

// ---------------------------------------------------------------------------
// Reduce 48 compact partials per element and mirror into full G.
// Grid: 8*15*1024/256 = 480 blocks. Reads coalesced; mirror store scattered
// but G is only 800 KB (L2-resident).
__global__ __launch_bounds__(256) void k_redG(const float* __restrict__ Gpart,
                                              float* __restrict__ G) {
    int idx = blockIdx.x * 256 + threadIdx.x;    // < 8*15360
    int b = idx / TSZ;
    int r = idx - b * TSZ;
    int t = r >> 10;
    int e = r & 1023;
    int er = e >> 5, ec = e & 31;
    int a, bb;
    tri_pair(t, a, bb);
    const float* gp = Gpart + (size_t)(b * NSPLIT) * TSZ + r;
    float s = 0.f;
#pragma unroll 8
    for (int k = 0; k < NSPLIT; ++k) s += gp[(size_t)k * TSZ];
    float* Gb = G + (size_t)b * GD;
    int i = a * 32 + er, j = bb * 32 + ec;
    Gb[i * Dn + j] = s;
    Gb[j * Dn + i] = s;      // diag tiles: symmetric pair writes identical value
}

// ---------------------------------------------------------------------------
// 4-step power-iteration chain on G (r10-proven eps-dropped NMF algebra).
__global__ __launch_bounds__(192) void k_chainB(const float* __restrict__ G,
                                                float* __restrict__ bases4,
                                                float* __restrict__ btb4) {
    __shared__ float bS[Dn];
    __shared__ float uS[Dn];
    __shared__ float sc[2];
    const int b = blockIdx.x;
    const int tid = threadIdx.x;
    const float* Gb = G + (size_t)b * GD;

    if (tid < Dn) bS[tid] = B0F;
    __syncthreads();

    float btb = BTB0;
#pragma unroll 1
    for (int j = 1; j <= 4; ++j) {
        if (tid < Dn) {
            float s = 0.f;
            const float* row = Gb + tid * Dn;
#pragma unroll 8
            for (int d = 0; d < Dn; ++d) s = fmaf(row[d], bS[d], s);
            uS[tid] = s;
        }
        __syncthreads();
        if (tid == 0) {
            float bgb = 0.f;
            for (int d = 0; d < Dn; ++d) bgb = fmaf(bS[d], uS[d], bgb);
            sc[0] = bgb;
        }
        __syncthreads();
        float denom = (j == 1) ? (btb + EPSF) : btb;
        float ctc = sc[0] / (denom * denom);
        float inv = 1.f / (denom * ctc);
        if (tid < Dn) bS[tid] = uS[tid] * inv;
        __syncthreads();
        if (tid == 0) {
            float ss = 0.f;
            for (int d = 0; d < Dn; ++d) ss = fmaf(bS[d], bS[d], ss);
            sc[1] = ss;
        }
        __syncthreads();
        btb = sc[1];
    }
    if (tid < Dn) bases4[b * Dn + tid] = bS[tid];
    if (tid == 0) btb4[b] = btb;
}

// ---------------------------------------------------------------------------
// Final coef: coef5[n] = (X^T b4)[n] / btb4 (r10-proven).
__global__ __launch_bounds__(256, 3) void k_coef5(
        const u16* __restrict__ h, float* __restrict__ coef,
        const float* __restrict__ bases4, const float* __restrict__ btb4)
{
    __shared__ float bsS[Dn];
    __shared__ float partA[4][128];
    const int blk = blockIdx.x;
    const int b   = blk / 144;
    const int cb  = blk - b * 144;
    const int colbase = cb * 128;
    const int tid = threadIdx.x, c8 = tid & 15, rg = tid >> 4;

    if (tid < Dn) bsS[tid] = bases4[b * Dn + tid] / btb4[b];
    __syncthreads();

    const u16* hp = h + (size_t)b * PB + colbase + c8 * 8;
    float acc[8];
#pragma unroll
    for (int j = 0; j < 8; ++j) acc[j] = 0.f;
#pragma unroll
    for (int k = 0; k < 10; ++k) {
        uint4 v = *reinterpret_cast<const uint4*>(hp + (size_t)(rg + 16 * k) * Nn);
        float w = bsS[rg + 16 * k];
        u32 vv[4] = { v.x, v.y, v.z, v.w };
#pragma unroll
        for (int q = 0; q < 4; ++q) {
            acc[2*q]   = fmaf(w, bf2f((u16)(vv[q] & 0xffffu)), acc[2*q]);
            acc[2*q+1] = fmaf(w, bf2f((u16)(vv[q] >> 16)),     acc[2*q+1]);
        }
    }
#pragma unroll
    for (int j = 0; j < 8; ++j) {
        acc[j] += __shfl_xor(acc[j], 16, 64);
        acc[j] += __shfl_xor(acc[j], 32, 64);
    }
    if ((tid & 48) == 0) {
        int w = tid >> 6;
#pragma unroll
        for (int j = 0; j < 8; ++j) partA[w][c8 * 8 + j] = acc[j];
    }
    __syncthreads();

    if (tid < 128)
        coef[(size_t)b * Nn + colbase + tid] =
            partA[0][tid] + partA[1][tid] + partA[2][tid] + partA[3][tid];
}

// ---------------------------------------------------------------------------
// Final output (r1-proven): out[b,o,t,hw] = coef5[n] * v[o,tau];
// relu(coef*u) == coef*relu(u) since coef5 >= 0. Grid 8*160, 192 thr.
__global__ __launch_bounds__(192) void k_post(const float* __restrict__ coef,
                                              const float* __restrict__ bases,
                                              const float* __restrict__ Wp1,
                                              const float* __restrict__ Wp2,
                                              float* __restrict__ out) {
    int b = blockIdx.x / Tn;
    int t = blockIdx.x - b * Tn;
    int tau = t >> 3;
    float u[8];
#pragma unroll
    for (int p = 0; p < 8; ++p) {
        float s = 0.f;
#pragma unroll
        for (int ca = 0; ca < 8; ++ca)
            s = fmaf(Wp1[p * 8 + ca], bases[b * Dn + ca * 20 + tau], s);
        u[p] = fmaxf(s, 0.f);
    }
    float v[16];
#pragma unroll
    for (int o = 0; o < 16; ++o) {
        float s = 0.f;
#pragma unroll
        for (int p = 0; p < 8; ++p) s = fmaf(Wp2[o * 8 + p], u[p], s);
        v[o] = s;
    }
    const float4* c4 = reinterpret_cast<const float4*>(coef + (size_t)b * Nn + (t & 7) * HWn);
    float4* o4 = reinterpret_cast<float4*>(out) + (size_t)(b * 16 * Tn + t) * (HWn / 4);
#pragma unroll
    for (int it = 0; it < 3; ++it) {
        int p4 = threadIdx.x + it * 192;
        float4 cv = c4[p4];
#pragma unroll
        for (int o = 0; o < 16; ++o) {
            float4 ov = make_float4(cv.x * v[o], cv.y * v[o], cv.z * v[o], cv.w * v[o]);
            o4[(size_t)o * (Tn * (HWn / 4)) + p4] = ov;
        }
    }
}

// ---------------------------------------------------------------------------
extern "C" void kernel_launch(void* const* d_in, const int* in_sizes, int n_in,
                              void* d_out, int out_size, void* d_ws, size_t ws_size,
                              hipStream_t stream) {
    const float* x    = (const float*)d_in[0];
    const float* Wpre = (const float*)d_in[1];
    const float* Wp1  = (const float*)d_in[2];
    const float* Wp2  = (const float*)d_in[3];
    float* out = (float*)d_out;

    // d_out: h (47 MB bf16) | G (820 KB) | Gpart compact (23.6 MB) — all
    // consumed before k_post rewrites d_out (k_post reads only ws).
    // No atomics anywhere -> deterministic, no init kernel.
    u16*   h     = (u16*)d_out;
    float* G     = out + G_OFF;
    float* Gpart = out + GP_OFF;
    float* ws = (float*)d_ws;
    float* coef   = ws + OFF_COEF;
    float* bases4 = ws + OFF_B4;
    float* btb4   = ws + OFF_BTB;

    k_pre<<<Bn * PLANE4 / 256, 256, 0, stream>>>(x, Wpre, h);
    k_gram<<<Bn * NSPLIT, 256, 0, stream>>>(h, Gpart);
    k_redG<<<Bn * TSZ / 256, 256, 0, stream>>>(Gpart, G);
    k_chainB<<<Bn, 192, 0, stream>>>(G, bases4, btb4);
    k_coef5<<<Bn * 144, 256, 0, stream>>>(h, coef, bases4, btb4);
    k_post<<<Bn * Tn, 192, 0, stream>>>(coef, bases4, Wp1, Wp2, out);
}